// Round 2
// baseline (974.484 us; speedup 1.0000x reference)
//
#include <hip/hip_runtime.h>
#include <stdint.h>

typedef _Float16 half8 __attribute__((ext_vector_type(8)));
typedef float f32x4 __attribute__((ext_vector_type(4)));

constexpr int E_EDGES = 800000;
constexpr int HD = 128;          // hidden dim
constexpr int RS = 136;          // LDS h row stride in halves: 272 B = 16B-aligned, odd dword count

// Pack W1 [256x128] and W2 [128x128] (row-major f32) into f16 MFMA B-fragment layout:
// frag element t = ((ks*8 + nt)*64 + lane)*8 + j  holds  W[k = ks*32 + (lane>>4)*8 + j][n = nt*16 + (lane&15)]
__global__ __launch_bounds__(256) void pack_weights(
    const float* __restrict__ W1, const float* __restrict__ W2,
    _Float16* __restrict__ W1p, _Float16* __restrict__ W2p)
{
    int t = blockIdx.x * 256 + threadIdx.x;
    if (t < 32768) {                     // W1: 8 ks * 8 nt * 64 * 8
        int j = t & 7, lane = (t >> 3) & 63, nt = (t >> 9) & 7, ks = t >> 12;
        int k = ks * 32 + (lane >> 4) * 8 + j;
        int n = nt * 16 + (lane & 15);
        W1p[t] = (_Float16)W1[k * HD + n];
    } else if (t < 49152) {              // W2: 4 ks * 8 nt * 64 * 8
        int q = t - 32768;
        int j = q & 7, lane = (q >> 3) & 63, nt = (q >> 9) & 7, ks = q >> 12;
        int k = ks * 32 + (lane >> 4) * 8 + j;
        int n = nt * 16 + (lane & 15);
        W2p[q] = (_Float16)W2[k * HD + n];
    }
}

// Block = 256 threads = 4 waves; each wave owns 32 edges (2 M-tiles of 16) x all 128 output cols.
__global__ __launch_bounds__(256, 2) void edge_update(
    const float* __restrict__ node_inv,
    const float* __restrict__ edge_feat,
    const int* __restrict__ esrc,        // harness delivers int64 reference indices as int32
    const int* __restrict__ edst,
    const float* __restrict__ b1v,
    const float* __restrict__ b2v,
    const float* __restrict__ gammav,
    const float* __restrict__ betav,
    const _Float16* __restrict__ W1p,
    const _Float16* __restrict__ W2p,
    float* __restrict__ out)
{
    __shared__ __align__(16) _Float16 hl[4 * 32 * RS];

    const int tid  = threadIdx.x;
    const int lane = tid & 63;
    const int w    = tid >> 6;
    const int quad = lane >> 4;
    const int c    = lane & 15;
    const int rb   = blockIdx.x * 128 + w * 32;   // wave's first edge row
    const int rA0  = rb + c;                      // A-operand row, m-tile 0  (A: m = lane&15)
    const int rA1  = rb + 16 + c;                 // A-operand row, m-tile 1

    const int s0 = esrc[rA0], d0 = edst[rA0];
    const int s1 = esrc[rA1], d1 = edst[rA1];

    f32x4 acc[2][8];
#pragma unroll
    for (int nt = 0; nt < 8; ++nt) {
        float bv = b1v[nt * 16 + c];              // C/D: col = nt*16 + (lane&15), same for all 4 regs
        acc[0][nt] = (f32x4){bv, bv, bv, bv};
        acc[1][nt] = acc[0][nt];
    }

    // ---------------- GEMM1: X[rb..rb+31, 0:256] @ W1 -> h, K = 8 steps of 32 ----------------
#pragma unroll
    for (int ks = 0; ks < 8; ++ks) {
        const int k0 = ks * 32 + quad * 8;        // A: k = (lane>>4)*8 + j within the 32-wide step
        const float *pa0, *pa1;
        if (ks < 2) {            // X[:, 0:64)   = node_inv[src]
            pa0 = node_inv + (long long)s0 * 64 + k0;
            pa1 = node_inv + (long long)s1 * 64 + k0;
        } else if (ks < 4) {     // X[:, 64:128) = node_inv[dst]
            pa0 = node_inv + (long long)d0 * 64 + (k0 - 64);
            pa1 = node_inv + (long long)d1 * 64 + (k0 - 64);
        } else {                 // X[:, 128:256) = edge_features
            pa0 = edge_feat + (long long)rA0 * HD + (k0 - 128);
            pa1 = edge_feat + (long long)rA1 * HD + (k0 - 128);
        }
        float4 x00 = ((const float4*)pa0)[0];
        float4 x01 = ((const float4*)pa0)[1];
        float4 x10 = ((const float4*)pa1)[0];
        float4 x11 = ((const float4*)pa1)[1];
        half8 a0, a1;
        a0[0]=(_Float16)x00.x; a0[1]=(_Float16)x00.y; a0[2]=(_Float16)x00.z; a0[3]=(_Float16)x00.w;
        a0[4]=(_Float16)x01.x; a0[5]=(_Float16)x01.y; a0[6]=(_Float16)x01.z; a0[7]=(_Float16)x01.w;
        a1[0]=(_Float16)x10.x; a1[1]=(_Float16)x10.y; a1[2]=(_Float16)x10.z; a1[3]=(_Float16)x10.w;
        a1[4]=(_Float16)x11.x; a1[5]=(_Float16)x11.y; a1[6]=(_Float16)x11.z; a1[7]=(_Float16)x11.w;
#pragma unroll
        for (int nt = 0; nt < 8; ++nt) {
            half8 b = *(const half8*)(W1p + (((ks * 8 + nt) * 64 + lane) << 3));
            acc[0][nt] = __builtin_amdgcn_mfma_f32_16x16x32_f16(a0, b, acc[0][nt], 0, 0, 0);
            acc[1][nt] = __builtin_amdgcn_mfma_f32_16x16x32_f16(a1, b, acc[1][nt], 0, 0, 0);
        }
    }

    // ---------------- ReLU + C-layout -> row-major h in LDS (f16) ----------------
    _Float16* hw = hl + w * 32 * RS;
#pragma unroll
    for (int m = 0; m < 2; ++m)
#pragma unroll
        for (int nt = 0; nt < 8; ++nt)
#pragma unroll
            for (int r = 0; r < 4; ++r) {
                float v = acc[m][nt][r];
                v = v > 0.f ? v : 0.f;
                // C/D: row = quad*4 + r, col = nt*16 + c
                hw[(m * 16 + quad * 4 + r) * RS + nt * 16 + c] = (_Float16)v;
            }
    __syncthreads();

    // ---------------- GEMM2: h[32x128] @ W2, K = 4 steps of 32 ----------------
#pragma unroll
    for (int nt = 0; nt < 8; ++nt) {
        float bv = b2v[nt * 16 + c];
        acc[0][nt] = (f32x4){bv, bv, bv, bv};
        acc[1][nt] = acc[0][nt];
    }
#pragma unroll
    for (int ks = 0; ks < 4; ++ks) {
        half8 a0 = *(const half8*)(hw + c * RS + ks * 32 + quad * 8);
        half8 a1 = *(const half8*)(hw + (16 + c) * RS + ks * 32 + quad * 8);
#pragma unroll
        for (int nt = 0; nt < 8; ++nt) {
            half8 b = *(const half8*)(W2p + (((ks * 8 + nt) * 64 + lane) << 3));
            acc[0][nt] = __builtin_amdgcn_mfma_f32_16x16x32_f16(a0, b, acc[0][nt], 0, 0, 0);
            acc[1][nt] = __builtin_amdgcn_mfma_f32_16x16x32_f16(a1, b, acc[1][nt], 0, 0, 0);
        }
    }

    // ---------------- LayerNorm (in-wave: each quad owns whole rows) + residual ----------------
    float gv[8], btv[8];
#pragma unroll
    for (int nt = 0; nt < 8; ++nt) {
        gv[nt]  = gammav[nt * 16 + c];
        btv[nt] = betav[nt * 16 + c];
    }

#pragma unroll
    for (int m = 0; m < 2; ++m) {
        float sum[4] = {0, 0, 0, 0}, sq[4] = {0, 0, 0, 0};
#pragma unroll
        for (int nt = 0; nt < 8; ++nt)
#pragma unroll
            for (int r = 0; r < 4; ++r) {
                float v = acc[m][nt][r];
                sum[r] += v;
                sq[r]  += v * v;
            }
        // reduce across the 16 lanes of the quad (rows are quad-local)
#pragma unroll
        for (int mask = 1; mask < 16; mask <<= 1)
#pragma unroll
            for (int r = 0; r < 4; ++r) {
                sum[r] += __shfl_xor(sum[r], mask);
                sq[r]  += __shfl_xor(sq[r], mask);
            }
        float mu[4], rstd[4];
#pragma unroll
        for (int r = 0; r < 4; ++r) {
            mu[r] = sum[r] * (1.0f / 128.0f);
            float var = sq[r] * (1.0f / 128.0f) - mu[r] * mu[r];
            rstd[r] = rsqrtf(var + 1e-5f);
        }
        const int rowg = rb + m * 16 + quad * 4;
#pragma unroll
        for (int nt = 0; nt < 8; ++nt)
#pragma unroll
            for (int r = 0; r < 4; ++r) {
                long long idx = (long long)(rowg + r) * HD + nt * 16 + c;
                out[idx] = edge_feat[idx] + (acc[m][nt][r] - mu[r]) * rstd[r] * gv[nt] + btv[nt];
            }
    }
}

extern "C" void kernel_launch(void* const* d_in, const int* in_sizes, int n_in,
                              void* d_out, int out_size, void* d_ws, size_t ws_size,
                              hipStream_t stream)
{
    const float* node_inv  = (const float*)d_in[0];
    const float* edge_feat = (const float*)d_in[1];
    const int*   esrc      = (const int*)d_in[2];
    const int*   edst      = (const int*)d_in[3];
    const float* W1        = (const float*)d_in[4];
    const float* b1        = (const float*)d_in[5];
    const float* W2        = (const float*)d_in[6];
    const float* b2        = (const float*)d_in[7];
    const float* gamma     = (const float*)d_in[8];
    const float* beta      = (const float*)d_in[9];

    _Float16* W1p = (_Float16*)d_ws;          // 32768 halves = 64 KB
    _Float16* W2p = W1p + 32768;              // 16384 halves = 32 KB

    pack_weights<<<192, 256, 0, stream>>>(W1, W2, W1p, W2p);
    edge_update<<<E_EDGES / 128, 256, 0, stream>>>(node_inv, edge_feat, esrc, edst,
                                                   b1, b2, gamma, beta, W1p, W2p,
                                                   (float*)d_out);
}